// Round 6
// baseline (306.192 us; speedup 1.0000x reference)
//
#include <hip/hip_runtime.h>
#include <cstdint>

// ConvBnA int8 conv via i8 MFMA (exact: i32 accumulation).
// Pass 1a: weight int32 [co][ci][3][3] -> int8 [g][co][ci] (+ zero page)
// Pass 1b: x int32 NCHW -> int8 NHWC, register-only transpose
// Pass 2 : implicit GEMM, 128co x 128px tile, 256 thr / 4 waves (2x2),
//          BK=64, DOUBLE-buffered LDS (32KB -> 5 blocks/CU), r3-verified
//          sync skeleton: stage(t+1) -> counted vmcnt(4) -> barrier ->
//          {8 ds_read + 16 MFMA} -> barrier. [chunk][row] conflict-free LDS.
// Output: harness reads integer outputs as int32 -> store int.

typedef __attribute__((ext_vector_type(4))) int i32x4;
typedef __attribute__((ext_vector_type(2))) int i32x2;

#define C_IN   128
#define HW2    3136      // 56*56
#define OUT_NSTRIDE 802816  // 256*3136

// workspace layout (bytes)
#define XQ_BYTES 12845056            // 100352 * 128 int8
#define WQ_OFF   XQ_BYTES
#define WQ_BYTES 294912              // 9*256*128 int8
#define ZP_OFF   (WQ_OFF + WQ_BYTES) // 256 zero bytes (16B-aligned)

__device__ __forceinline__ void gload_lds16(const void* g, void* l) {
  __builtin_amdgcn_global_load_lds(
      (const __attribute__((address_space(1))) void*)(uintptr_t)g,
      (__attribute__((address_space(3))) void*)(uint32_t)(uintptr_t)l,
      16, 0, 0);
}

// ---------------- pass 1a: weight -> int8 [g][co][ci] + zero page ----------------
__global__ void wxform(const int* __restrict__ w, char* __restrict__ wq,
                       int* __restrict__ zp) {
  int id = blockIdx.x * 256 + threadIdx.x;      // over 9*256*128 = 294912
  int ci = id & 127;
  int co = (id >> 7) & 255;
  int g  = id >> 15;                            // kh*3+kw
  wq[id] = (char)w[co * 1152 + ci * 9 + g];
  if (blockIdx.x == 0 && threadIdx.x < 64) zp[threadIdx.x] = 0;
}

// ---------------- pass 1b: x NCHW int32 -> NHWC int8, reg-only transpose ----------------
__global__ __launch_bounds__(256) void xform(const int* __restrict__ x,
                                             char* __restrict__ xq) {
  int bid = blockIdx.x;                 // 32n * 49hb = 1568 blocks
  int hb = bid % 49;
  int n  = bid / 49;
  int t  = threadIdx.x;
  int cig = t & 15;                     // ci group (8 ci each)
  int hw0 = (t >> 4) * 4;               // 4 pixels
  const int* src = x + n * (C_IN * HW2) + hb * 64 + hw0;
  i32x4 ld[8];
#pragma unroll
  for (int j = 0; j < 8; j++)
    ld[j] = *(const i32x4*)(src + (cig * 8 + j) * HW2);
  char* dst = xq + (size_t)(n * HW2 + hb * 64 + hw0) * 128 + cig * 8;
#pragma unroll
  for (int p = 0; p < 4; p++) {
    unsigned lo = (ld[0][p] & 255) | ((ld[1][p] & 255) << 8) |
                  ((ld[2][p] & 255) << 16) | ((unsigned)(ld[3][p] & 255) << 24);
    unsigned hi = (ld[4][p] & 255) | ((ld[5][p] & 255) << 8) |
                  ((ld[6][p] & 255) << 16) | ((unsigned)(ld[7][p] & 255) << 24);
    i32x2 v; v[0] = (int)lo; v[1] = (int)hi;
    *(i32x2*)(dst + p * 128) = v;
  }
}

// ---------------- pass 2: i8 MFMA implicit GEMM, r3 skeleton @ BK=64 ----------------
__global__ __launch_bounds__(256, 5) void conv_mfma(
    const char* __restrict__ xq, const char* __restrict__ wq,
    const char* __restrict__ zp,
    const int* __restrict__ nshift, const int* __restrict__ tbias,
    const int* __restrict__ aminp, const int* __restrict__ amaxp,
    int* __restrict__ out) {
  __shared__ char lds[32768];   // 2 bufs x (A 8KB + B 8KB)
  // per buf: [chunk c(4)][row r(128)] 16B units; addr = (c*128+r)*16.
  // ds_read_b128: lanes 0..15 consecutive rows -> 256B contiguous (0 conflicts, r5-verified)

  const int tid = threadIdx.x;
  const int bid = blockIdx.x;
  // XCD-aware bijective swizzle: 1568 = 8 * 196
  const int swz = (bid & 7) * 196 + (bid >> 3);
  const int bm = swz / 784;       // co half (0..1)
  const int pb = swz % 784;       // pixel block
  const int l   = tid & 63;
  const int wid = tid >> 6;
  const int wm = wid >> 1, wn = wid & 1;   // 2x2 waves, 64x64 tile each

  // ---- staging geometry: thread handles slots tid, tid+256 of 512 (16B each)
  const int r_ = tid & 127;       // row (co for A / px for B), same both chunks
  const int cA = tid >> 7;        // chunk 0..1 (second: +2)
  const char* wbase = wq + (bm * 128 + r_) * 128;   // + g*32768 + kh*64 + c*16
  const int p = pb * 128 + r_;
  const int n_img = p / HW2;
  const int hw = p - n_img * HW2;
  const int ph = hw / 56, pw = hw - ph * 56;
  const char* xbase = xq + (size_t)p * 128;

  auto stage = [&](int s, char* buf) {    // s = step index (g = s>>1, kh = s&1)
    const int g = s >> 1, kh = s & 1;
    char* Ab = buf;
    char* Bb = buf + 8192;
    const char* as = wbase + g * 32768 + kh * 64;
    gload_lds16(as + cA * 16,       Ab + (cA * 128 + r_) * 16);
    gload_lds16(as + (cA + 2) * 16, Ab + ((cA + 2) * 128 + r_) * 16);
    const int g3 = g / 3;
    const int dh = g3 - 1, dw = g - g3 * 3 - 1;
    const bool valid = ((unsigned)(ph + dh) < 56u) && ((unsigned)(pw + dw) < 56u);
    const char* bs = valid ? (xbase + (dh * 56 + dw) * 128 + kh * 64) : zp;
    gload_lds16(bs + cA * 16,       Bb + (cA * 128 + r_) * 16);
    gload_lds16(bs + (cA + 2) * 16, Bb + ((cA + 2) * 128 + r_) * 16);
  };

  i32x4 acc[4][4] = {};
  const int lr16 = (l & 15) * 16;
  const int lch  = l >> 4;               // k-chunk 0..3 (K=64 = 4 x 16B)

  // prologue: step 0 staged
  stage(0, lds);

#pragma unroll 1
  for (int t = 0; t < 18; ++t) {
    // r3 skeleton: issue next stage FIRST, then counted wait, then barrier
    if (t < 17) stage(t + 1, lds + ((t + 1) & 1) * 16384);
    __builtin_amdgcn_sched_barrier(0);
    if (t < 17) { asm volatile("s_waitcnt vmcnt(4)" ::: "memory"); }
    else        { asm volatile("s_waitcnt vmcnt(0)" ::: "memory"); }
    __builtin_amdgcn_s_barrier();
    __builtin_amdgcn_sched_barrier(0);
    char* Ab = lds + (t & 1) * 16384;
    char* Bb = Ab + 8192;
    i32x4 a[4], b[4];
#pragma unroll
    for (int mi = 0; mi < 4; mi++)
      a[mi] = *(const i32x4*)(Ab + (lch * 128 + wm * 64 + mi * 16) * 16 + lr16);
#pragma unroll
    for (int ni = 0; ni < 4; ni++)
      b[ni] = *(const i32x4*)(Bb + (lch * 128 + wn * 64 + ni * 16) * 16 + lr16);
    __builtin_amdgcn_s_setprio(1);
#pragma unroll
    for (int mi = 0; mi < 4; mi++)
#pragma unroll
      for (int ni = 0; ni < 4; ni++)
        acc[mi][ni] = __builtin_amdgcn_mfma_i32_16x16x64_i8(
            a[mi], b[ni], acc[mi][ni], 0, 0, 0);
    __builtin_amdgcn_s_setprio(0);
    __builtin_amdgcn_sched_barrier(0);
    __builtin_amdgcn_s_barrier();
    __builtin_amdgcn_sched_barrier(0);
  }

  // ---- epilogue: +t, >> (-n), clamp, store int32 (r3-verified mapping) ----
  const int amin = aminp[0], amax = amaxp[0];
  int pbase[4];
#pragma unroll
  for (int ni = 0; ni < 4; ni++) {
    int pp = pb * 128 + wn * 64 + ni * 16 + (l & 15);
    int nn = pp / HW2;
    int hh = pp - nn * HW2;
    pbase[ni] = nn * OUT_NSTRIDE + hh;
  }
#pragma unroll
  for (int mi = 0; mi < 4; mi++) {
    int co0 = bm * 128 + wm * 64 + mi * 16 + (lch << 2);
    const int4 t4 = *(const int4*)(tbias + co0);
    const int4 n4 = *(const int4*)(nshift + co0);
#pragma unroll
    for (int ni = 0; ni < 4; ni++) {
#pragma unroll
      for (int r = 0; r < 4; r++) {
        int tv = (r == 0) ? t4.x : (r == 1) ? t4.y : (r == 2) ? t4.z : t4.w;
        int nv = (r == 0) ? n4.x : (r == 1) ? n4.y : (r == 2) ? n4.z : n4.w;
        int v = acc[mi][ni][r] + tv;
        v = v >> (-nv);                       // arithmetic shift
        v = v < amin ? amin : (v > amax ? amax : v);
        out[pbase[ni] + (co0 + r) * HW2] = v;
      }
    }
  }
}

extern "C" void kernel_launch(void* const* d_in, const int* in_sizes, int n_in,
                              void* d_out, int out_size, void* d_ws, size_t ws_size,
                              hipStream_t stream) {
  const int* x      = (const int*)d_in[0];
  const int* w      = (const int*)d_in[1];
  const int* nshift = (const int*)d_in[2];
  const int* tbias  = (const int*)d_in[3];
  const int* aminp  = (const int*)d_in[4];
  const int* amaxp  = (const int*)d_in[5];
  int* out = (int*)d_out;

  char* xq = (char*)d_ws;
  char* wq = (char*)d_ws + WQ_OFF;
  char* zp = (char*)d_ws + ZP_OFF;

  hipLaunchKernelGGL(wxform, dim3(1152), dim3(256), 0, stream, w, wq, (int*)zp);
  hipLaunchKernelGGL(xform,  dim3(1568), dim3(256), 0, stream, x, xq);
  hipLaunchKernelGGL(conv_mfma, dim3(1568), dim3(256), 0, stream,
                     xq, wq, zp, nshift, tbias, aminp, amaxp, out);
}

// Round 8
// 182.488 us; speedup vs baseline: 1.6779x; 1.6779x over previous
//
#include <hip/hip_runtime.h>
#include <cstdint>

// ConvBnA int8 conv via i8 MFMA (exact: i32 accumulation).
// Pass 1 (fused): x NCHW int32 -> int8 NHWC (reg-only transpose) AND
//                 weight int32 [co][ci][3][3] -> int8 [g][co][ci] (+ zero page)
// Pass 2 : r3-VERBATIM conv: implicit GEMM, M=256, N=100352, K=9*128,
//          BK=128/tap (9 steps), 128x128 tile, 4 waves, 16x16x64 i8 MFMA,
//          double-buffered 64KB LDS, global_load_lds w=16, counted vmcnt(8),
//          XOR chunk-swizzle, 32-MFMA clusters between barrier pairs.
// Output: harness reads integer outputs as int32 -> store int.

typedef __attribute__((ext_vector_type(4))) int i32x4;
typedef __attribute__((ext_vector_type(2))) int i32x2;

#define C_IN   128
#define HW2    3136      // 56*56
#define OUT_NSTRIDE 802816  // 256*3136

// workspace layout (bytes)
#define XQ_BYTES 12845056            // 100352 * 128 int8
#define WQ_OFF   XQ_BYTES
#define WQ_BYTES 294912              // 9*256*128 int8
#define ZP_OFF   (WQ_OFF + WQ_BYTES) // 256 zero bytes (16B-aligned)

__device__ __forceinline__ void gload_lds16(const void* g, void* l) {
  __builtin_amdgcn_global_load_lds(
      (const __attribute__((address_space(1))) void*)(uintptr_t)g,
      (__attribute__((address_space(3))) void*)(uint32_t)(uintptr_t)l,
      16, 0, 0);
}

// ---------------- pass 1 (fused): x transpose + weight pack ----------------
__global__ __launch_bounds__(256) void prep(const int* __restrict__ x,
                                            const int* __restrict__ w,
                                            char* __restrict__ xq,
                                            char* __restrict__ wq,
                                            int* __restrict__ zp) {
  int bid = blockIdx.x;
  if (bid >= 1568) {                    // weight pack: blocks 1568..2719
    int id = (bid - 1568) * 256 + threadIdx.x;   // over 9*256*128 = 294912
    int ci = id & 127;
    int co = (id >> 7) & 255;
    int g  = id >> 15;                  // kh*3+kw
    wq[id] = (char)w[co * 1152 + ci * 9 + g];
    if (bid == 1568 && threadIdx.x < 64) zp[threadIdx.x] = 0;
    return;
  }
  // x transpose: blocks 0..1567 (32n * 49hb)
  int hb = bid % 49;
  int n  = bid / 49;
  int t  = threadIdx.x;
  int cig = t & 15;                     // ci group (8 ci each)
  int hw0 = (t >> 4) * 4;               // 4 pixels
  const int* src = x + n * (C_IN * HW2) + hb * 64 + hw0;
  i32x4 ld[8];
#pragma unroll
  for (int j = 0; j < 8; j++)
    ld[j] = *(const i32x4*)(src + (cig * 8 + j) * HW2);
  char* dst = xq + (size_t)(n * HW2 + hb * 64 + hw0) * 128 + cig * 8;
#pragma unroll
  for (int p = 0; p < 4; p++) {
    unsigned lo = (ld[0][p] & 255) | ((ld[1][p] & 255) << 8) |
                  ((ld[2][p] & 255) << 16) | ((unsigned)(ld[3][p] & 255) << 24);
    unsigned hi = (ld[4][p] & 255) | ((ld[5][p] & 255) << 8) |
                  ((ld[6][p] & 255) << 16) | ((unsigned)(ld[7][p] & 255) << 24);
    i32x2 v; v[0] = (int)lo; v[1] = (int)hi;
    *(i32x2*)(dst + p * 128) = v;
  }
}

// ---------------- pass 2: i8 MFMA implicit GEMM (r3-verbatim) ----------------
__global__ __launch_bounds__(256, 2) void conv_mfma(
    const char* __restrict__ xq, const char* __restrict__ wq,
    const char* __restrict__ zp,
    const int* __restrict__ nshift, const int* __restrict__ tbias,
    const int* __restrict__ aminp, const int* __restrict__ amaxp,
    int* __restrict__ out) {
  __shared__ char lds[65536];   // 2 bufs x (A 16KB + B 16KB); row = 128B (128 ci int8)

  const int tid = threadIdx.x;
  const int bid = blockIdx.x;
  const int bm = bid & 1;        // co block (0..1)
  const int pb = bid >> 1;       // pixel block (0..783)
  const int l  = tid & 63;
  const int wid = tid >> 6;
  const int wm = wid >> 1, wn = wid & 1;   // 2x2 waves, 64x64 each

  // staging: slot j = tid + i*256; row = j>>3 (0..127), local chunk = j&7 (16B)
  // swizzle: local chunk chl holds global chunk chl ^ (row&7)
  const int chl = tid & 7;
  const int rsw = (tid >> 3) & 7;          // row&7, invariant in i (i*32)
  const int chg = chl ^ rsw;
  const int kboff = chg * 16;              // byte offset within 128B row

  int p_idx[4], p_h[4], p_w[4];
#pragma unroll
  for (int i = 0; i < 4; i++) {
    int pr = (tid >> 3) + i * 32;
    int p  = pb * 128 + pr;
    int n  = p / HW2;
    int hw = p - n * HW2;
    int h  = hw / 56;
    int w  = hw - h * 56;
    p_idx[i] = p; p_h[i] = h; p_w[i] = w;
  }

  auto stageAB = [&](int g, int buf) {
    char* Ab = lds + buf * 32768;
    char* Bb = Ab + 16384;
    const int dh = g / 3 - 1, dw = g % 3 - 1;
    const int doff = dh * 56 + dw;
    // A: weight tile [co 128][ci 128] int8
    const char* wsrc = wq + (((g * 256 + bm * 128)) << 7) + kboff;
#pragma unroll
    for (int i = 0; i < 4; i++) {
      int row = (tid >> 3) + i * 32;
      gload_lds16(wsrc + (row << 7), Ab + (tid + i * 256) * 16);
    }
    // B: x tile [pix 128][ci 128] int8, zero-page redirect for halo
#pragma unroll
    for (int i = 0; i < 4; i++) {
      int h2 = p_h[i] + dh, w2 = p_w[i] + dw;
      bool valid = ((unsigned)h2 < 56u) && ((unsigned)w2 < 56u);
      const char* gp = valid ? (xq + ((size_t)(p_idx[i] + doff) << 7) + kboff)
                             : zp;
      gload_lds16(gp, Bb + (tid + i * 256) * 16);
    }
  };

  i32x4 acc[4][4] = {};
  const int lrow = l & 15;
  const int lk   = (l >> 4) * 16;          // byte offset of lane's k-chunk
  const int lsw  = (l & 7) << 4;           // read-side swizzle XOR (row&7 == l&7)

  auto computeStep = [&](int buf) {
    char* Ab = lds + buf * 32768;
    char* Bb = Ab + 16384;
#pragma unroll
    for (int kk = 0; kk < 2; kk++) {       // K=128 per tap = 2 x K64 MFMA
      i32x4 a[4], b[4];
      const int cb = ((kk * 64 + lk) ^ lsw);
#pragma unroll
      for (int mi = 0; mi < 4; mi++) {
        int row = wm * 64 + mi * 16 + lrow;
        a[mi] = *(const i32x4*)(Ab + (row << 7) + cb);
      }
#pragma unroll
      for (int ni = 0; ni < 4; ni++) {
        int row = wn * 64 + ni * 16 + lrow;
        b[ni] = *(const i32x4*)(Bb + (row << 7) + cb);
      }
#pragma unroll
      for (int mi = 0; mi < 4; mi++)
#pragma unroll
        for (int ni = 0; ni < 4; ni++)
          acc[mi][ni] = __builtin_amdgcn_mfma_i32_16x16x64_i8(
              a[mi], b[ni], acc[mi][ni], 0, 0, 0);
    }
  };

  stageAB(0, 0);
#pragma unroll 1
  for (int s = 0; s < 9; ++s) {           // 9 taps, BK=128 each
    const int s1 = s + 1;
    if (s1 < 9) stageAB(s1, s1 & 1);
    __builtin_amdgcn_sched_barrier(0);
    if (s1 < 9) { asm volatile("s_waitcnt vmcnt(8)" ::: "memory"); }
    else        { asm volatile("s_waitcnt vmcnt(0)" ::: "memory"); }
    __builtin_amdgcn_s_barrier();
    __builtin_amdgcn_sched_barrier(0);
    computeStep(s & 1);
    __builtin_amdgcn_sched_barrier(0);
    __builtin_amdgcn_s_barrier();
    __builtin_amdgcn_sched_barrier(0);
  }

  // ---- epilogue: +t, >> (-n), clamp, store int32 ----
  const int amin = aminp[0], amax = amaxp[0];
  int pbase[4];
#pragma unroll
  for (int ni = 0; ni < 4; ni++) {
    int pp = pb * 128 + wn * 64 + ni * 16 + lrow;
    int nn = pp / HW2;
    int hh = pp - nn * HW2;
    pbase[ni] = nn * OUT_NSTRIDE + hh;
  }
#pragma unroll
  for (int mi = 0; mi < 4; mi++) {
    int co0 = bm * 128 + wm * 64 + mi * 16 + ((l >> 4) << 2);
    const int4 t4 = *(const int4*)(tbias + co0);
    const int4 n4 = *(const int4*)(nshift + co0);
#pragma unroll
    for (int ni = 0; ni < 4; ni++) {
#pragma unroll
      for (int r = 0; r < 4; r++) {
        int tv = (r == 0) ? t4.x : (r == 1) ? t4.y : (r == 2) ? t4.z : t4.w;
        int nv = (r == 0) ? n4.x : (r == 1) ? n4.y : (r == 2) ? n4.z : n4.w;
        int v = acc[mi][ni][r] + tv;
        v = v >> (-nv);                       // arithmetic shift
        v = v < amin ? amin : (v > amax ? amax : v);
        out[pbase[ni] + (co0 + r) * HW2] = v;
      }
    }
  }
}

extern "C" void kernel_launch(void* const* d_in, const int* in_sizes, int n_in,
                              void* d_out, int out_size, void* d_ws, size_t ws_size,
                              hipStream_t stream) {
  const int* x      = (const int*)d_in[0];
  const int* w      = (const int*)d_in[1];
  const int* nshift = (const int*)d_in[2];
  const int* tbias  = (const int*)d_in[3];
  const int* aminp  = (const int*)d_in[4];
  const int* amaxp  = (const int*)d_in[5];
  int* out = (int*)d_out;

  char* xq = (char*)d_ws;
  char* wq = (char*)d_ws + WQ_OFF;
  char* zp = (char*)d_ws + ZP_OFF;

  hipLaunchKernelGGL(prep, dim3(2720), dim3(256), 0, stream, x, w, xq, wq, (int*)zp);
  hipLaunchKernelGGL(conv_mfma, dim3(1568), dim3(256), 0, stream,
                     xq, wq, zp, nshift, tbias, aminp, amaxp, out);
}